// Round 2
// baseline (158.343 us; speedup 1.0000x reference)
//
#include <hip/hip_runtime.h>
#include <hip/hip_bf16.h>
#include <cstdint>

// Problem constants (features: [512, 16, 512] fp32 -> N=8192 rows, D=512)
#define N_TOT 8192
#define DDIM  512
#define DBYTES 512                     // bytes per row in fp8
#define NBLK  64                       // 8192 / 128 tile blocks per dim
#define NTRI  (NBLK * (NBLK + 1) / 2)  // 2080 lower-triangle blocks
constexpr float INV_T = 1.0f / 0.07f;

typedef uint8_t u8;
typedef __attribute__((ext_vector_type(8))) int i32x8_t;
typedef __attribute__((ext_vector_type(4))) float f32x4_t;

// ---- helpers ---------------------------------------------------------------

// async 16B global->LDS (global_load_lds_dwordx4). LDS dst is wave-uniform
// base + lane*16 (lane-contiguous) -- swizzle is applied to the GLOBAL src.
__device__ __forceinline__ void load16_to_lds(const void* g, void* l) {
  __builtin_amdgcn_global_load_lds(
      (const __attribute__((address_space(1))) unsigned int*)g,
      (__attribute__((address_space(3))) unsigned int*)l, 16, 0, 0);
}

// counted vmcnt wait (T4): memory clobber pins compiler-generated ds_reads
// AFTER the wait (they must not be hoisted above it).
#define WAIT_VMCNT(n) asm volatile("s_waitcnt vmcnt(" #n ")" ::: "memory")
// pin chunk issue order so per-thread vmcnt counting is chunk-accurate
#define CHUNK_FENCE()                          \
  do {                                         \
    __builtin_amdgcn_sched_barrier(0);         \
    asm volatile("" ::: "memory");             \
  } while (0)

// ---- kernel 1: row-normalize fp32 -> fp8 e4m3 (+ zero tsum and out) --------
// one wave per row; hw cvt_pk_fp8 (RNE, OCP e4m3 on gfx950). |x|<=1 so no sat.
__global__ __launch_bounds__(256) void normalize_kernel(const float* __restrict__ X,
                                                        u8* __restrict__ Xn,
                                                        float* __restrict__ tsum,
                                                        float* __restrict__ out) {
  if (blockIdx.x < 32) tsum[blockIdx.x * 256 + threadIdx.x] = 0.0f;
  if (blockIdx.x == 32 && threadIdx.x == 0) out[0] = 0.0f;
  const int lane = threadIdx.x & 63;
  const int row  = blockIdx.x * 4 + (threadIdx.x >> 6);
  const float4* xr = (const float4*)(X + (size_t)row * DDIM);
  float4 v0 = xr[lane];       // elements 4*lane .. +3
  float4 v1 = xr[lane + 64];  // elements 256+4*lane .. +3
  float s = v0.x * v0.x + v0.y * v0.y + v0.z * v0.z + v0.w * v0.w
          + v1.x * v1.x + v1.y * v1.y + v1.z * v1.z + v1.w * v1.w;
#pragma unroll
  for (int m = 1; m < 64; m <<= 1) s += __shfl_xor(s, m);
  const float scale = 1.0f / fmaxf(sqrtf(s), 1e-8f);
  int w0 = __builtin_amdgcn_cvt_pk_fp8_f32(v0.x * scale, v0.y * scale, 0, 0);
  w0     = __builtin_amdgcn_cvt_pk_fp8_f32(v0.z * scale, v0.w * scale, w0, 1);
  int w1 = __builtin_amdgcn_cvt_pk_fp8_f32(v1.x * scale, v1.y * scale, 0, 0);
  w1     = __builtin_amdgcn_cvt_pk_fp8_f32(v1.z * scale, v1.w * scale, w1, 1);
  uint32_t* orow = (uint32_t*)(Xn + (size_t)row * DBYTES);
  orow[lane]      = (uint32_t)w0;   // bytes 4*lane .. +3
  orow[lane + 64] = (uint32_t)w1;   // bytes 256+4*lane .. +3
}

// ---- kernel 2: lower-triangle tiles of C = Xn*Xn^T, fused exp row/col sums -
// MX-fp8: 128x128 tile, 256 threads = 4 waves in 2x2; each wave owns 64x64
// via 4x4 frags of mfma_scale 16x16x128 f8f6f4 (cbsz=blgp=0 -> e4m3, unit
// E8M0 scales 0x7F).
//
// R2: FULL-PANEL UPFRONT STAGING + COUNTED VMCNT (T4). D=512 -> the whole
// A panel (128x512B = 64 KB) and B panel (64 KB) fit in 128 KB LDS as 4
// K-chunks each. Issue ALL 32 per-thread global_load_lds at kernel start
// (chunk-ordered, fenced); consume chunk c after s_waitcnt vmcnt(24/16/8/0)
// + raw s_barrier. No buffer reuse -> no WAR hazard, no mid-kernel vmcnt(0)
// drains; L2 latency exposed once per block, chunk c+1's load BW hides under
// chunk c's ds_read+MFMA. 128 KB LDS -> 1 block/CU (deep in-block pipeline
// replaces inter-block overlap; occupancy counter will read ~12% by design).
//
// LDS XOR swizzle (verified 0-conflict structure, unchanged per chunk):
// granule (row, j) j=0..7 (16B each) at slot row*8 + (j ^ (row&7)); staging
// inverts the swizzle on the global source address.
__global__ __launch_bounds__(256) void gemm_exp_rowsum(const u8* __restrict__ Xn,
                                                       float* __restrict__ tsum) {
  __shared__ __align__(16) u8 sA[4][128 * 128];  // 64 KB: chunk c = K [c*128,c*128+128)
  __shared__ __align__(16) u8 sB[4][128 * 128];  // 64 KB

  // triangular decode: blockIdx.x -> (bi >= bj)
  const int k = blockIdx.x;
  int bi = (int)((sqrtf(8.0f * (float)k + 1.0f) - 1.0f) * 0.5f);
  while ((bi + 1) * (bi + 2) / 2 <= k) ++bi;
  while (bi * (bi + 1) / 2 > k) --bi;
  const int bj = k - bi * (bi + 1) / 2;
  const int rowBase = bi * 128;
  const int colBase = bj * 128;
  const bool isDiag = (bi == bj);

  const int t    = threadIdx.x;   // 0..255
  const int lane = t & 63;
  const int l15  = lane & 15;
  const int quad = lane >> 4;
  const int w    = t >> 6;        // 0..3
  const int wm   = w >> 1;        // 0..1: row offset wm*64
  const int wn   = w & 1;         // 0..1: col offset wn*64

  // staging: per panel-chunk 1024 granules of 16B (128 rows x 8); thread t
  // handles granules t, t+256, t+512, t+768 -> rows srow, +32, +64, +96,
  // same goff ((srow+32)&7 == srow&7).
  const int srow = t >> 3;
  const int goff = ((t & 7) ^ (srow & 7)) * 16;  // swizzle-inverted byte offset
  const u8* gA = Xn + (size_t)(rowBase + srow) * DBYTES + goff;
  const u8* gB = Xn + (size_t)(colBase + srow) * DBYTES + goff;

  // ---- issue ALL staging loads, chunk-ordered: 8 per thread per chunk ----
#pragma unroll
  for (int c = 0; c < 4; ++c) {
    const int k0 = c * 128;
#pragma unroll
    for (int r = 0; r < 4; ++r) {
      load16_to_lds(gA + (size_t)(r * 32) * DBYTES + k0, sA[c] + t * 16 + r * 4096);
      load16_to_lds(gB + (size_t)(r * 32) * DBYTES + k0, sB[c] + t * 16 + r * 4096);
    }
    CHUNK_FENCE();  // per-thread vmcnt counts must align with chunk boundary
  }

  f32x4_t acc[4][4];
#pragma unroll
  for (int i = 0; i < 4; i++)
#pragma unroll
    for (int j = 0; j < 4; j++) acc[i][j] = {0.f, 0.f, 0.f, 0.f};

  // fragment addressing (chunk-invariant; compiler CSEs across chunks)
  const int arow[4] = {wm * 64 + 0 * 16 + l15, wm * 64 + 1 * 16 + l15,
                       wm * 64 + 2 * 16 + l15, wm * 64 + 3 * 16 + l15};
  const int brow[4] = {wn * 64 + 0 * 16 + l15, wn * 64 + 1 * 16 + l15,
                       wn * 64 + 2 * 16 + l15, wn * 64 + 3 * 16 + l15};

#define COMPUTE_CHUNK(c)                                                      \
  do {                                                                        \
    i32x8_t a[4], b[4];                                                       \
    _Pragma("unroll") for (int mi = 0; mi < 4; mi++) {                        \
      const int row = arow[mi];                                               \
      const int s0 = ((quad * 2) ^ (row & 7)) * 16;                           \
      const int s1 = ((quad * 2 + 1) ^ (row & 7)) * 16;                       \
      int4 lo = *(const int4*)&sA[c][row * 128 + s0];                         \
      int4 hi = *(const int4*)&sA[c][row * 128 + s1];                         \
      a[mi] = (i32x8_t){lo.x, lo.y, lo.z, lo.w, hi.x, hi.y, hi.z, hi.w};      \
    }                                                                         \
    _Pragma("unroll") for (int ni = 0; ni < 4; ni++) {                        \
      const int row = brow[ni];                                               \
      const int s0 = ((quad * 2) ^ (row & 7)) * 16;                           \
      const int s1 = ((quad * 2 + 1) ^ (row & 7)) * 16;                       \
      int4 lo = *(const int4*)&sB[c][row * 128 + s0];                         \
      int4 hi = *(const int4*)&sB[c][row * 128 + s1];                         \
      b[ni] = (i32x8_t){lo.x, lo.y, lo.z, lo.w, hi.x, hi.y, hi.z, hi.w};      \
    }                                                                         \
    __builtin_amdgcn_s_setprio(1);                                            \
    _Pragma("unroll") for (int mi = 0; mi < 4; mi++)                          \
        _Pragma("unroll") for (int ni = 0; ni < 4; ni++)                      \
            acc[mi][ni] = __builtin_amdgcn_mfma_scale_f32_16x16x128_f8f6f4(   \
                a[mi], b[ni], acc[mi][ni], 0, 0, 0, 0x7F7F7F7Fu, 0,           \
                0x7F7F7F7Fu);                                                 \
    __builtin_amdgcn_s_setprio(0);                                            \
  } while (0)

  // consume: wait own chunk-c loads (in-order vmcnt retirement), barrier so
  // ALL threads' chunk-c granules are in LDS, then compute. Loads for chunks
  // c+1..3 stay in flight across the barrier -- never drain to 0 early.
  WAIT_VMCNT(24);
  __builtin_amdgcn_s_barrier();
  COMPUTE_CHUNK(0);
  WAIT_VMCNT(16);
  __builtin_amdgcn_s_barrier();
  COMPUTE_CHUNK(1);
  WAIT_VMCNT(8);
  __builtin_amdgcn_s_barrier();
  COMPUTE_CHUNK(2);
  WAIT_VMCNT(0);
  __builtin_amdgcn_s_barrier();
  COMPUTE_CHUNK(3);

  // epilogue: e = exp((c-1)/T). C/D layout: col = lane&15, row = quad*4 + reg
  // (shape-determined, dtype-independent -- m121..m128).
  if (isDiag) {
#pragma unroll
    for (int mi = 0; mi < 4; mi++) {
#pragma unroll
      for (int r = 0; r < 4; r++) {
        const int row = rowBase + wm * 64 + mi * 16 + quad * 4 + r;
        float rs = 0.0f;
#pragma unroll
        for (int ni = 0; ni < 4; ni++) {
          const int col = colBase + wn * 64 + ni * 16 + l15;
          const float e = __expf((acc[mi][ni][r] - 1.0f) * INV_T);
          rs += (row == col) ? 0.0f : e;
        }
        rs += __shfl_xor(rs, 1);
        rs += __shfl_xor(rs, 2);
        rs += __shfl_xor(rs, 4);
        rs += __shfl_xor(rs, 8);
        if (l15 == 0) atomicAdd(&tsum[row], rs);
      }
    }
  } else {
    float csum[4] = {0.f, 0.f, 0.f, 0.f};
#pragma unroll
    for (int mi = 0; mi < 4; mi++) {
#pragma unroll
      for (int r = 0; r < 4; r++) {
        const int row = rowBase + wm * 64 + mi * 16 + quad * 4 + r;
        float rs = 0.0f;
#pragma unroll
        for (int ni = 0; ni < 4; ni++) {
          const float e = __expf((acc[mi][ni][r] - 1.0f) * INV_T);
          rs += e;
          csum[ni] += e;
        }
        rs += __shfl_xor(rs, 1);
        rs += __shfl_xor(rs, 2);
        rs += __shfl_xor(rs, 4);
        rs += __shfl_xor(rs, 8);
        if (l15 == 0) atomicAdd(&tsum[row], rs);
      }
    }
#pragma unroll
    for (int ni = 0; ni < 4; ni++) {
      csum[ni] += __shfl_xor(csum[ni], 16);
      csum[ni] += __shfl_xor(csum[ni], 32);
      if (quad == 0) atomicAdd(&tsum[colBase + wn * 64 + ni * 16 + l15], csum[ni]);
    }
  }
#undef COMPUTE_CHUNK
}

// ---- kernel 3: loss = mean_i log1p(t_i), 32 blocks + atomic accumulate -----
__global__ __launch_bounds__(256) void finalize_kernel(const float* __restrict__ tsum,
                                                       float* __restrict__ out) {
  const int i = blockIdx.x * 256 + threadIdx.x;
  float s = log1pf(tsum[i]);
#pragma unroll
  for (int m = 1; m < 64; m <<= 1) s += __shfl_xor(s, m);
  __shared__ float ws[4];
  if ((threadIdx.x & 63) == 0) ws[threadIdx.x >> 6] = s;
  __syncthreads();
  if (threadIdx.x == 0)
    atomicAdd(out, (ws[0] + ws[1] + ws[2] + ws[3]) * (1.0f / N_TOT));
}

// ---- launcher --------------------------------------------------------------
extern "C" void kernel_launch(void* const* d_in, const int* in_sizes, int n_in,
                              void* d_out, int out_size, void* d_ws, size_t ws_size,
                              hipStream_t stream) {
  const float* X = (const float*)d_in[0];
  float* out = (float*)d_out;

  float* tsum = (float*)d_ws;                       // 8192 fp32 = 32 KB
  u8* Xn = (u8*)d_ws + 65536;                       // 8192x512 fp8 = 4 MB

  normalize_kernel<<<N_TOT / 4, 256, 0, stream>>>(X, Xn, tsum, out);
  gemm_exp_rowsum<<<NTRI, 256, 0, stream>>>(Xn, tsum);
  finalize_kernel<<<N_TOT / 256, 256, 0, stream>>>(tsum, out);
}

// Round 3
// 135.111 us; speedup vs baseline: 1.1719x; 1.1719x over previous
//
#include <hip/hip_runtime.h>
#include <hip/hip_bf16.h>
#include <cstdint>

// Problem constants (features: [512, 16, 512] fp32 -> N=8192 rows, D=512)
#define N_TOT 8192
#define DDIM  512
#define DBYTES 512                       // bytes per row in fp8
#define NBLK2 32                         // 8192 / 256 tile blocks per dim
#define NTRI2 (NBLK2 * (NBLK2 + 1) / 2)  // 528 lower-triangle blocks
constexpr float INV_T = 1.0f / 0.07f;

typedef uint8_t u8;
typedef __attribute__((ext_vector_type(8))) int i32x8_t;
typedef __attribute__((ext_vector_type(4))) float f32x4_t;

// ---- helpers ---------------------------------------------------------------

// async 16B global->LDS (global_load_lds_dwordx4). LDS dst is wave-uniform
// base + lane*16 (lane-contiguous) -- swizzle is applied to the GLOBAL src.
__device__ __forceinline__ void load16_to_lds(const void* g, void* l) {
  __builtin_amdgcn_global_load_lds(
      (const __attribute__((address_space(1))) unsigned int*)g,
      (__attribute__((address_space(3))) unsigned int*)l, 16, 0, 0);
}

#define WAIT_VMCNT(n) asm volatile("s_waitcnt vmcnt(" #n ")" ::: "memory")
#define WAIT_LGKM0()                                  \
  do {                                                \
    asm volatile("s_waitcnt lgkmcnt(0)" ::: "memory");\
    __builtin_amdgcn_sched_barrier(0);                \
  } while (0)

// ---- kernel 1: row-normalize fp32 -> fp8 e4m3 (+ zero tsum and out) --------
// one wave per row; hw cvt_pk_fp8 (RNE, OCP e4m3 on gfx950). |x|<=1 so no sat.
__global__ __launch_bounds__(256) void normalize_kernel(const float* __restrict__ X,
                                                        u8* __restrict__ Xn,
                                                        float* __restrict__ tsum,
                                                        float* __restrict__ out) {
  if (blockIdx.x < 32) tsum[blockIdx.x * 256 + threadIdx.x] = 0.0f;
  if (blockIdx.x == 32 && threadIdx.x == 0) out[0] = 0.0f;
  const int lane = threadIdx.x & 63;
  const int row  = blockIdx.x * 4 + (threadIdx.x >> 6);
  const float4* xr = (const float4*)(X + (size_t)row * DDIM);
  float4 v0 = xr[lane];       // elements 4*lane .. +3
  float4 v1 = xr[lane + 64];  // elements 256+4*lane .. +3
  float s = v0.x * v0.x + v0.y * v0.y + v0.z * v0.z + v0.w * v0.w
          + v1.x * v1.x + v1.y * v1.y + v1.z * v1.z + v1.w * v1.w;
#pragma unroll
  for (int m = 1; m < 64; m <<= 1) s += __shfl_xor(s, m);
  const float scale = 1.0f / fmaxf(sqrtf(s), 1e-8f);
  int w0 = __builtin_amdgcn_cvt_pk_fp8_f32(v0.x * scale, v0.y * scale, 0, 0);
  w0     = __builtin_amdgcn_cvt_pk_fp8_f32(v0.z * scale, v0.w * scale, w0, 1);
  int w1 = __builtin_amdgcn_cvt_pk_fp8_f32(v1.x * scale, v1.y * scale, 0, 0);
  w1     = __builtin_amdgcn_cvt_pk_fp8_f32(v1.z * scale, v1.w * scale, w1, 1);
  uint32_t* orow = (uint32_t*)(Xn + (size_t)row * DBYTES);
  orow[lane]      = (uint32_t)w0;   // bytes 4*lane .. +3
  orow[lane + 64] = (uint32_t)w1;   // bytes 256+4*lane .. +3
}

// ---- kernel 2: lower-triangle tiles of C = Xn*Xn^T, fused exp row/col sums -
//
// R3: 256x256 tile, 8-phase-style schedule (m201 template ported to MX-fp8).
// 512 threads = 8 waves (2M x 4N); each wave owns 128x64 = 8x4 frags of
// mfma_scale 16x16x128 f8f6f4 (cbsz=blgp=0 -> e4m3, unit E8M0 scales 0x7F).
// BK=128 bytes -> K=512 is 4 K-steps; LDS = dbuf x (A 32KB + B 32KB) = 128KB
// -> 1 block/CU, but 8 waves = 2/SIMD give intra-block wave overlap (R2's
// failure was 1 wave/SIMD). Per K-step, 2 phases:
//   P0: ds_read b[0..3]+a[0..3]; barrier; lgkm0; setprio1; 16 MFMA; barrier.
//   P1: ds_read a[4..7];        barrier; lgkm0; setprio1; 16 MFMA; barrier.
// Next K-step's 8 global_load_lds are issued at the TOP of each K-step
// (target buffer certified free by prior step's trailing barrier) and
// awaited with counted vmcnt(8) a full K-step later -- T4: never an
// immediate drain, loads stay in flight across barriers.
//
// LDS XOR swizzle (verified structure): granule (row, j) j=0..7 (16B) at
// slot row*8 + (j ^ (row&7)); staging inverts the swizzle on the global src.
__global__ __launch_bounds__(512, 2) void gemm_exp_rowsum(const u8* __restrict__ Xn,
                                                          float* __restrict__ tsum) {
  __shared__ __align__(16) u8 sA[2][256 * 128];  // 2 x 32 KB
  __shared__ __align__(16) u8 sB[2][256 * 128];  // 2 x 32 KB

  // triangular decode: blockIdx.x -> (bi >= bj)
  const int k = blockIdx.x;
  int bi = (int)((sqrtf(8.0f * (float)k + 1.0f) - 1.0f) * 0.5f);
  while ((bi + 1) * (bi + 2) / 2 <= k) ++bi;
  while (bi * (bi + 1) / 2 > k) --bi;
  const int bj = k - bi * (bi + 1) / 2;
  const int rowBase = bi * 256;
  const int colBase = bj * 256;
  const bool isDiag = (bi == bj);

  const int t    = threadIdx.x;   // 0..511
  const int lane = t & 63;
  const int l15  = lane & 15;
  const int quad = lane >> 4;
  const int w    = t >> 6;        // 0..7
  const int wm   = w >> 2;        // 0..1: row offset wm*128
  const int wn   = w & 3;         // 0..3: col offset wn*64

  // staging: per panel-K-step 2048 granules of 16B (256 rows x 8); thread t
  // handles granules t, +512, +1024, +1536 -> rows srow, +64, +128, +192,
  // same goff ((srow+64)&7 == srow&7).
  const int srow = t >> 3;                       // 0..63
  const int goff = ((t & 7) ^ (srow & 7)) * 16;  // swizzle-inverted byte off
  const u8* gA = Xn + (size_t)(rowBase + srow) * DBYTES + goff;
  const u8* gB = Xn + (size_t)(colBase + srow) * DBYTES + goff;

  // ---- prologue: stage K-step 0 into buffer 0 (await at KSTEP(0)) ----
#pragma unroll
  for (int r = 0; r < 4; ++r) {
    load16_to_lds(gA + (size_t)(r * 64) * DBYTES, sA[0] + t * 16 + r * 8192);
    load16_to_lds(gB + (size_t)(r * 64) * DBYTES, sB[0] + t * 16 + r * 8192);
  }

  f32x4_t acc[8][4];
#pragma unroll
  for (int i = 0; i < 8; i++)
#pragma unroll
    for (int j = 0; j < 4; j++) acc[i][j] = {0.f, 0.f, 0.f, 0.f};

  i32x8_t a[4], b[4];  // a reused across P0/P1 to cap VGPR pressure

#define READ_FRAG(dst, S, rowe)                                               \
  do {                                                                        \
    const int row = (rowe);                                                   \
    const int s0 = ((quad * 2) ^ (row & 7)) * 16;                             \
    const int s1 = ((quad * 2 + 1) ^ (row & 7)) * 16;                         \
    int4 lo = *(const int4*)&(S)[row * 128 + s0];                             \
    int4 hi = *(const int4*)&(S)[row * 128 + s1];                             \
    dst = (i32x8_t){lo.x, lo.y, lo.z, lo.w, hi.x, hi.y, hi.z, hi.w};          \
  } while (0)

#define KSTEP(n, NV, ISSUE)                                                   \
  do {                                                                        \
    if (ISSUE) { /* issue step n+1 loads into buf ~cur (freed last step) */   \
      const int k0 = ((n) + 1) * 128;                                         \
      _Pragma("unroll") for (int r = 0; r < 4; ++r) {                         \
        load16_to_lds(gA + (size_t)(r * 64) * DBYTES + k0,                    \
                      sA[((n) + 1) & 1] + t * 16 + r * 8192);                 \
        load16_to_lds(gB + (size_t)(r * 64) * DBYTES + k0,                    \
                      sB[((n) + 1) & 1] + t * 16 + r * 8192);                 \
      }                                                                       \
    }                                                                         \
    WAIT_VMCNT(NV); /* counted: step n's 8 landed; n+1's 8 stay in flight */  \
    __builtin_amdgcn_s_barrier();                                             \
    /* ---- P0: b[0..3] + a[0..3] ---- */                                     \
    _Pragma("unroll") for (int ni = 0; ni < 4; ++ni)                          \
        READ_FRAG(b[ni], sB[(n) & 1], wn * 64 + ni * 16 + l15);               \
    _Pragma("unroll") for (int mi = 0; mi < 4; ++mi)                          \
        READ_FRAG(a[mi], sA[(n) & 1], wm * 128 + mi * 16 + l15);              \
    __builtin_amdgcn_s_barrier();                                             \
    WAIT_LGKM0();                                                             \
    __builtin_amdgcn_s_setprio(1);                                            \
    _Pragma("unroll") for (int mi = 0; mi < 4; ++mi)                          \
        _Pragma("unroll") for (int ni = 0; ni < 4; ++ni)                      \
            acc[mi][ni] = __builtin_amdgcn_mfma_scale_f32_16x16x128_f8f6f4(   \
                a[mi], b[ni], acc[mi][ni], 0, 0, 0, 0x7F7F7F7Fu, 0,           \
                0x7F7F7F7Fu);                                                 \
    __builtin_amdgcn_s_setprio(0);                                            \
    __builtin_amdgcn_s_barrier();                                             \
    /* ---- P1: a[4..7] ---- */                                               \
    _Pragma("unroll") for (int mi = 0; mi < 4; ++mi)                          \
        READ_FRAG(a[mi], sA[(n) & 1], wm * 128 + (mi + 4) * 16 + l15);        \
    __builtin_amdgcn_s_barrier();                                             \
    WAIT_LGKM0();                                                             \
    __builtin_amdgcn_s_setprio(1);                                            \
    _Pragma("unroll") for (int mi = 0; mi < 4; ++mi)                          \
        _Pragma("unroll") for (int ni = 0; ni < 4; ++ni)                      \
            acc[mi + 4][ni] = __builtin_amdgcn_mfma_scale_f32_16x16x128_f8f6f4(\
                a[mi], b[ni], acc[mi + 4][ni], 0, 0, 0, 0x7F7F7F7Fu, 0,       \
                0x7F7F7F7Fu);                                                 \
    __builtin_amdgcn_s_setprio(0);                                            \
    __builtin_amdgcn_s_barrier(); /* certifies buf cur free for step n+2 */   \
  } while (0)

  KSTEP(0, 8, 1);
  KSTEP(1, 8, 1);
  KSTEP(2, 8, 1);
  KSTEP(3, 0, 0);

#undef KSTEP
#undef READ_FRAG

  // epilogue: e = exp((c-1)/T). C/D layout: col = lane&15, row = quad*4 + reg
  // (shape-determined, dtype-independent -- m121..m128).
  if (isDiag) {
    // diagonal tile is symmetric: row sums only (col sums would double-count)
#pragma unroll
    for (int mi = 0; mi < 8; mi++) {
#pragma unroll
      for (int r = 0; r < 4; r++) {
        const int row = rowBase + wm * 128 + mi * 16 + quad * 4 + r;
        float rs = 0.0f;
#pragma unroll
        for (int ni = 0; ni < 4; ni++) {
          const int col = colBase + wn * 64 + ni * 16 + l15;
          const float e = __expf((acc[mi][ni][r] - 1.0f) * INV_T);
          rs += (row == col) ? 0.0f : e;
        }
        rs += __shfl_xor(rs, 1);
        rs += __shfl_xor(rs, 2);
        rs += __shfl_xor(rs, 4);
        rs += __shfl_xor(rs, 8);
        if (l15 == 0) atomicAdd(&tsum[row], rs);
      }
    }
  } else {
    float csum[4] = {0.f, 0.f, 0.f, 0.f};
#pragma unroll
    for (int mi = 0; mi < 8; mi++) {
#pragma unroll
      for (int r = 0; r < 4; r++) {
        const int row = rowBase + wm * 128 + mi * 16 + quad * 4 + r;
        float rs = 0.0f;
#pragma unroll
        for (int ni = 0; ni < 4; ni++) {
          const float e = __expf((acc[mi][ni][r] - 1.0f) * INV_T);
          rs += e;
          csum[ni] += e;
        }
        rs += __shfl_xor(rs, 1);
        rs += __shfl_xor(rs, 2);
        rs += __shfl_xor(rs, 4);
        rs += __shfl_xor(rs, 8);
        if (l15 == 0) atomicAdd(&tsum[row], rs);
      }
    }
#pragma unroll
    for (int ni = 0; ni < 4; ni++) {
      csum[ni] += __shfl_xor(csum[ni], 16);
      csum[ni] += __shfl_xor(csum[ni], 32);
      if (quad == 0) atomicAdd(&tsum[colBase + wn * 64 + ni * 16 + l15], csum[ni]);
    }
  }
}

// ---- kernel 3: loss = mean_i log1p(t_i), 32 blocks + atomic accumulate -----
__global__ __launch_bounds__(256) void finalize_kernel(const float* __restrict__ tsum,
                                                       float* __restrict__ out) {
  const int i = blockIdx.x * 256 + threadIdx.x;
  float s = log1pf(tsum[i]);
#pragma unroll
  for (int m = 1; m < 64; m <<= 1) s += __shfl_xor(s, m);
  __shared__ float ws[4];
  if ((threadIdx.x & 63) == 0) ws[threadIdx.x >> 6] = s;
  __syncthreads();
  if (threadIdx.x == 0)
    atomicAdd(out, (ws[0] + ws[1] + ws[2] + ws[3]) * (1.0f / N_TOT));
}

// ---- launcher --------------------------------------------------------------
extern "C" void kernel_launch(void* const* d_in, const int* in_sizes, int n_in,
                              void* d_out, int out_size, void* d_ws, size_t ws_size,
                              hipStream_t stream) {
  const float* X = (const float*)d_in[0];
  float* out = (float*)d_out;

  float* tsum = (float*)d_ws;                       // 8192 fp32 = 32 KB
  u8* Xn = (u8*)d_ws + 65536;                       // 8192x512 fp8 = 4 MB

  normalize_kernel<<<N_TOT / 4, 256, 0, stream>>>(X, Xn, tsum, out);
  gemm_exp_rowsum<<<NTRI2, 512, 0, stream>>>(Xn, tsum);
  finalize_kernel<<<N_TOT / 256, 256, 0, stream>>>(tsum, out);
}

// Round 5
// 115.363 us; speedup vs baseline: 1.3726x; 1.1712x over previous
//
#include <hip/hip_runtime.h>
#include <hip/hip_bf16.h>
#include <cstdint>

// Problem constants (features: [512, 16, 512] fp32 -> N=8192 rows, D=512)
#define N_TOT 8192
#define DDIM  512
#define DBYTES 512                     // bytes per row in fp8
#define NBLK  64                       // 8192 / 128 tile blocks per dim
#define NTRI  (NBLK * (NBLK + 1) / 2)  // 2080 lower-triangle blocks
constexpr float INV_T = 1.0f / 0.07f;

typedef uint8_t u8;
typedef __attribute__((ext_vector_type(8))) int i32x8_t;
typedef __attribute__((ext_vector_type(4))) float f32x4_t;

// ---- helpers ---------------------------------------------------------------

// async 16B global->LDS (global_load_lds_dwordx4). LDS dst is wave-uniform
// base + lane*16 (lane-contiguous) -- swizzle is applied to the GLOBAL src.
__device__ __forceinline__ void load16_to_lds(const void* g, void* l) {
  __builtin_amdgcn_global_load_lds(
      (const __attribute__((address_space(1))) unsigned int*)g,
      (__attribute__((address_space(3))) unsigned int*)l, 16, 0, 0);
}

// VALU-pipe cross-lane add via DPP row_shr (16-lane row). Replaces ds_swizzle
// (LDS pipe) shuffles in the reduce -- the LDS pipe is the measured bottleneck
// (R0 accounting: ~28 us of 56 us on LDS pipe; VALU only 18% busy).
// After shr 1,2,4,8 adds, lane 15 of each 16-lane group holds the group sum.
// NOTE: dpp_ctrl must be a compile-time constant -> template parameter.
template <int CTRL>
__device__ __forceinline__ float dpp_shr_add(float v) {
  int sh = __builtin_amdgcn_update_dpp(0, __builtin_bit_cast(int, v),
                                       CTRL, 0xF, 0xF, true);
  return v + __builtin_bit_cast(float, sh);
}
#define DPP_ROW_SHR1 0x111
#define DPP_ROW_SHR2 0x112
#define DPP_ROW_SHR4 0x114
#define DPP_ROW_SHR8 0x118

// ---- kernel 1: row-normalize fp32 -> fp8 e4m3 (+ zero tsum and out) --------
// one wave per row; hw cvt_pk_fp8 (RNE, OCP e4m3 on gfx950). |x|<=1 so no sat.
__global__ __launch_bounds__(256) void normalize_kernel(const float* __restrict__ X,
                                                        u8* __restrict__ Xn,
                                                        float* __restrict__ tsum,
                                                        float* __restrict__ out) {
  if (blockIdx.x < 32) tsum[blockIdx.x * 256 + threadIdx.x] = 0.0f;
  if (blockIdx.x == 32 && threadIdx.x == 0) out[0] = 0.0f;
  const int lane = threadIdx.x & 63;
  const int row  = blockIdx.x * 4 + (threadIdx.x >> 6);
  const float4* xr = (const float4*)(X + (size_t)row * DDIM);
  float4 v0 = xr[lane];       // elements 4*lane .. +3
  float4 v1 = xr[lane + 64];  // elements 256+4*lane .. +3
  float s = v0.x * v0.x + v0.y * v0.y + v0.z * v0.z + v0.w * v0.w
          + v1.x * v1.x + v1.y * v1.y + v1.z * v1.z + v1.w * v1.w;
#pragma unroll
  for (int m = 1; m < 64; m <<= 1) s += __shfl_xor(s, m);
  const float scale = 1.0f / fmaxf(sqrtf(s), 1e-8f);
  int w0 = __builtin_amdgcn_cvt_pk_fp8_f32(v0.x * scale, v0.y * scale, 0, 0);
  w0     = __builtin_amdgcn_cvt_pk_fp8_f32(v0.z * scale, v0.w * scale, w0, 1);
  int w1 = __builtin_amdgcn_cvt_pk_fp8_f32(v1.x * scale, v1.y * scale, 0, 0);
  w1     = __builtin_amdgcn_cvt_pk_fp8_f32(v1.z * scale, v1.w * scale, w1, 1);
  uint32_t* orow = (uint32_t*)(Xn + (size_t)row * DBYTES);
  orow[lane]      = (uint32_t)w0;   // bytes 4*lane .. +3
  orow[lane + 64] = (uint32_t)w1;   // bytes 256+4*lane .. +3
}

// ---- kernel 2: lower-triangle tiles of C = Xn*Xn^T, fused exp row/col sums -
// R5 = R0 skeleton (best measured: 56 us) + DPP epilogue + 4 blocks/CU.
// MX-fp8 path: 128x128 tile, BK=128 bytes (4 K-iters), 256 threads = 4 waves
// in 2x2; each wave owns 64x64 via 4x4 frags of mfma_scale 16x16x128 f8f6f4
// (cbsz=blgp=0 -> e4m3, unit E8M0 scales 0x7F). Single-buffered 32 KB LDS.
// NO device-scope fences. Inter-block TLP (4 blocks/CU, phase-diverse) is the
// latency-hiding mechanism -- deep in-block pipelines measured WORSE (R2/R3).
// LDS XOR swizzle: granule (row, j) j=0..7 (16B each) stored at slot
// row*8 + (j ^ (row&7)); staging inverts the swizzle on the global source.
__global__ __launch_bounds__(256, 4) void gemm_exp_rowsum(const u8* __restrict__ Xn,
                                                          float* __restrict__ tsum) {
  __shared__ __align__(16) u8 sA[128 * 128];  // 16 KB
  __shared__ __align__(16) u8 sB[128 * 128];  // 16 KB

  // triangular decode: blockIdx.x -> (bi >= bj)
  const int k = blockIdx.x;
  int bi = (int)((sqrtf(8.0f * (float)k + 1.0f) - 1.0f) * 0.5f);
  while ((bi + 1) * (bi + 2) / 2 <= k) ++bi;
  while (bi * (bi + 1) / 2 > k) --bi;
  const int bj = k - bi * (bi + 1) / 2;
  const int rowBase = bi * 128;
  const int colBase = bj * 128;
  const bool isDiag = (bi == bj);

  const int t    = threadIdx.x;   // 0..255
  const int lane = t & 63;
  const int l15  = lane & 15;
  const int quad = lane >> 4;
  const int w    = t >> 6;        // 0..3
  const int wm   = w >> 1;        // 0..1: row offset wm*64
  const int wn   = w & 1;         // 0..1: col offset wn*64

  f32x4_t acc[4][4];
#pragma unroll
  for (int i = 0; i < 4; i++)
#pragma unroll
    for (int j = 0; j < 4; j++) acc[i][j] = {0.f, 0.f, 0.f, 0.f};

  // staging: per panel 1024 granules of 16B (128 rows x 8); thread t handles
  // granules t, t+256, t+512, t+768 -> rows srow, +32, +64, +96, same goff
  // ((srow+32)&7 == srow&7).
  const int srow = t >> 3;
  const int goff = ((t & 7) ^ (srow & 7)) * 16;  // swizzle-inverted byte offset
  const u8* gA = Xn + (size_t)(rowBase + srow) * DBYTES + goff;
  const u8* gB = Xn + (size_t)(colBase + srow) * DBYTES + goff;
  u8* lA = sA + t * 16;
  u8* lB = sB + t * 16;

  for (int k0 = 0; k0 < DBYTES; k0 += 128) {  // 4 iters
#pragma unroll
    for (int r = 0; r < 4; r++) {
      load16_to_lds(gA + (size_t)(r * 32) * DBYTES + k0, lA + r * 4096);
      load16_to_lds(gB + (size_t)(r * 32) * DBYTES + k0, lB + r * 4096);
    }
    __syncthreads();

    i32x8_t a[4], b[4];
#pragma unroll
    for (int mi = 0; mi < 4; mi++) {
      const int row = wm * 64 + mi * 16 + l15;
      const int s0 = ((quad * 2) ^ (row & 7)) * 16;
      const int s1 = ((quad * 2 + 1) ^ (row & 7)) * 16;
      int4 lo = *(const int4*)&sA[row * 128 + s0];
      int4 hi = *(const int4*)&sA[row * 128 + s1];
      a[mi] = (i32x8_t){lo.x, lo.y, lo.z, lo.w, hi.x, hi.y, hi.z, hi.w};
    }
#pragma unroll
    for (int ni = 0; ni < 4; ni++) {
      const int row = wn * 64 + ni * 16 + l15;
      const int s0 = ((quad * 2) ^ (row & 7)) * 16;
      const int s1 = ((quad * 2 + 1) ^ (row & 7)) * 16;
      int4 lo = *(const int4*)&sB[row * 128 + s0];
      int4 hi = *(const int4*)&sB[row * 128 + s1];
      b[ni] = (i32x8_t){lo.x, lo.y, lo.z, lo.w, hi.x, hi.y, hi.z, hi.w};
    }

#pragma unroll
    for (int mi = 0; mi < 4; mi++)
#pragma unroll
      for (int ni = 0; ni < 4; ni++)
        acc[mi][ni] = __builtin_amdgcn_mfma_scale_f32_16x16x128_f8f6f4(
            a[mi], b[ni], acc[mi][ni], 0, 0, 0, 0x7F7F7F7Fu, 0, 0x7F7F7F7Fu);
    __syncthreads();
  }

  // epilogue: e = exp((c-1)/T). C/D layout: col = lane&15, row = quad*4 + reg
  // (shape-determined, dtype-independent -- m121..m128).
  // Row-sum reduction over l15 via DPP row_shr on the VALU pipe (NOT the LDS
  // pipe): sum lands in lane 15 of each 16-lane group. Col-sums keep the 8
  // cheap shuffles/wave (quad-axis xor16/xor32).
  if (isDiag) {
#pragma unroll
    for (int mi = 0; mi < 4; mi++) {
#pragma unroll
      for (int r = 0; r < 4; r++) {
        const int row = rowBase + wm * 64 + mi * 16 + quad * 4 + r;
        float rs = 0.0f;
#pragma unroll
        for (int ni = 0; ni < 4; ni++) {
          const int col = colBase + wn * 64 + ni * 16 + l15;
          const float e = __expf((acc[mi][ni][r] - 1.0f) * INV_T);
          rs += (row == col) ? 0.0f : e;
        }
        rs = dpp_shr_add<DPP_ROW_SHR1>(rs);
        rs = dpp_shr_add<DPP_ROW_SHR2>(rs);
        rs = dpp_shr_add<DPP_ROW_SHR4>(rs);
        rs = dpp_shr_add<DPP_ROW_SHR8>(rs);
        if (l15 == 15) atomicAdd(&tsum[row], rs);
      }
    }
  } else {
    float csum[4] = {0.f, 0.f, 0.f, 0.f};
#pragma unroll
    for (int mi = 0; mi < 4; mi++) {
#pragma unroll
      for (int r = 0; r < 4; r++) {
        const int row = rowBase + wm * 64 + mi * 16 + quad * 4 + r;
        float rs = 0.0f;
#pragma unroll
        for (int ni = 0; ni < 4; ni++) {
          const float e = __expf((acc[mi][ni][r] - 1.0f) * INV_T);
          rs += e;
          csum[ni] += e;
        }
        rs = dpp_shr_add<DPP_ROW_SHR1>(rs);
        rs = dpp_shr_add<DPP_ROW_SHR2>(rs);
        rs = dpp_shr_add<DPP_ROW_SHR4>(rs);
        rs = dpp_shr_add<DPP_ROW_SHR8>(rs);
        if (l15 == 15) atomicAdd(&tsum[row], rs);
      }
    }
#pragma unroll
    for (int ni = 0; ni < 4; ni++) {
      csum[ni] += __shfl_xor(csum[ni], 16);
      csum[ni] += __shfl_xor(csum[ni], 32);
      if (quad == 0) atomicAdd(&tsum[colBase + wn * 64 + ni * 16 + l15], csum[ni]);
    }
  }
}

// ---- kernel 3: loss = mean_i log1p(t_i), 32 blocks + atomic accumulate -----
__global__ __launch_bounds__(256) void finalize_kernel(const float* __restrict__ tsum,
                                                       float* __restrict__ out) {
  const int i = blockIdx.x * 256 + threadIdx.x;
  float s = log1pf(tsum[i]);
#pragma unroll
  for (int m = 1; m < 64; m <<= 1) s += __shfl_xor(s, m);
  __shared__ float ws[4];
  if ((threadIdx.x & 63) == 0) ws[threadIdx.x >> 6] = s;
  __syncthreads();
  if (threadIdx.x == 0)
    atomicAdd(out, (ws[0] + ws[1] + ws[2] + ws[3]) * (1.0f / N_TOT));
}

// ---- launcher --------------------------------------------------------------
extern "C" void kernel_launch(void* const* d_in, const int* in_sizes, int n_in,
                              void* d_out, int out_size, void* d_ws, size_t ws_size,
                              hipStream_t stream) {
  const float* X = (const float*)d_in[0];
  float* out = (float*)d_out;

  float* tsum = (float*)d_ws;                       // 8192 fp32 = 32 KB
  u8* Xn = (u8*)d_ws + 65536;                       // 8192x512 fp8 = 4 MB

  normalize_kernel<<<N_TOT / 4, 256, 0, stream>>>(X, Xn, tsum, out);
  gemm_exp_rowsum<<<NTRI, 256, 0, stream>>>(Xn, tsum);
  finalize_kernel<<<N_TOT / 256, 256, 0, stream>>>(tsum, out);
}